// Round 4
// baseline (62.284 us; speedup 1.0000x reference)
//
#include <hip/hip_runtime.h>

#define N 4096
#define F 64
#define H 8
#define RCHUNKS 128   // row chunks for partial column sums (32 rows each)

// ---------------------------------------------------------------------------
// Kernel 1: partial column sums of A.
// grid (4, RCHUNKS), block 256. Each thread owns 4 consecutive columns
// (float4 load), accumulates 32 rows. Coalesced 1KB/wave per instruction.
// ---------------------------------------------------------------------------
__global__ __launch_bounds__(256) void colsum_partial(const float* __restrict__ A,
                                                      float* __restrict__ partial) {
    int c4 = blockIdx.x * 256 + threadIdx.x;      // 0..1023 -> columns c4*4 .. c4*4+3
    int r0 = blockIdx.y * (N / RCHUNKS);
    const float* p = A + (size_t)r0 * N + (size_t)c4 * 4;
    float4 acc = make_float4(0.f, 0.f, 0.f, 0.f);
    for (int r = 0; r < N / RCHUNKS; ++r) {
        float4 v = *(const float4*)p;
        acc.x += v.x; acc.y += v.y; acc.z += v.z; acc.w += v.w;
        p += N;
    }
    *(float4*)(partial + (size_t)blockIdx.y * N + (size_t)c4 * 4) = acc;
}

// ---------------------------------------------------------------------------
// Kernel 2: finalize sum_w, compute aj[4096][8] and bk[4096][8].
//   aj[n][k] = b1[k] + sum_f E[n][f] * W1[k][f]
//   bk[n][k] = sum_w[n] * W1[k][128] + sum_f E[n][f] * W1[k][64+f]
// E[n][f] = emb[f*N + n]  (coalesced across threads).
// W1 reads are wave-uniform -> scalar loads / L1 broadcast.
// ---------------------------------------------------------------------------
__global__ __launch_bounds__(256) void build_ajbk(const float* __restrict__ A,
                                                  const float* __restrict__ emb,
                                                  const float* __restrict__ W1,
                                                  const float* __restrict__ b1,
                                                  const float* __restrict__ partial,
                                                  float* __restrict__ aj,
                                                  float* __restrict__ bk) {
    int n = blockIdx.x * 256 + threadIdx.x;
    float s = 0.f;
    for (int p = 0; p < RCHUNKS; ++p) s += partial[(size_t)p * N + n];
    float sum_w = (s - A[(size_t)n * N + n]) * (1.0f / (float)(N - 1));

    float e[F];
#pragma unroll
    for (int f = 0; f < F; ++f) e[f] = emb[(size_t)f * N + n];

#pragma unroll
    for (int k = 0; k < H; ++k) {
        float a = b1[k];
        float b = sum_w * W1[k * (2 * F + 1) + 2 * F];
#pragma unroll
        for (int f = 0; f < F; ++f) {
            a += e[f] * W1[k * (2 * F + 1) + f];
            b += e[f] * W1[k * (2 * F + 1) + F + f];
        }
        aj[n * H + k] = a;
        bk[n * H + k] = b;
    }
}

// ---------------------------------------------------------------------------
// Kernel 3: fused outer product + 8-wide relu-dot.
//   out[i][j] = b2[0] + sum_k relu(aj[i][k] + bk[j][k]) * W2[0][k]
// Tile: 32 rows x 128 cols per 256-thread block.
// tx = tid&31 -> 4 consecutive columns (float4 store); ty = tid>>5 -> 4 rows.
// bk for the 4 columns + w2 live in registers; aj row reads are L1 broadcast.
// ---------------------------------------------------------------------------
__global__ __launch_bounds__(256) void fuse_out(const float* __restrict__ aj,
                                                const float* __restrict__ bk,
                                                const float* __restrict__ W2,
                                                const float* __restrict__ b2,
                                                float* __restrict__ out) {
    int tx = threadIdx.x & 31;
    int ty = threadIdx.x >> 5;
    int j  = blockIdx.x * 128 + tx * 4;
    int i0 = blockIdx.y * 32 + ty * 4;

    float w2[H];
#pragma unroll
    for (int k = 0; k < H; ++k) w2[k] = W2[k];   // W2[0][k]
    float b20 = b2[0];

    float bks[4][H];
#pragma unroll
    for (int c = 0; c < 4; ++c) {
        float4 lo = *(const float4*)(bk + (size_t)(j + c) * H);
        float4 hi = *(const float4*)(bk + (size_t)(j + c) * H + 4);
        bks[c][0] = lo.x; bks[c][1] = lo.y; bks[c][2] = lo.z; bks[c][3] = lo.w;
        bks[c][4] = hi.x; bks[c][5] = hi.y; bks[c][6] = hi.z; bks[c][7] = hi.w;
    }

#pragma unroll
    for (int r = 0; r < 4; ++r) {
        int i = i0 + r;
        float a[H];
        float4 lo = *(const float4*)(aj + (size_t)i * H);
        float4 hi = *(const float4*)(aj + (size_t)i * H + 4);
        a[0] = lo.x; a[1] = lo.y; a[2] = lo.z; a[3] = lo.w;
        a[4] = hi.x; a[5] = hi.y; a[6] = hi.z; a[7] = hi.w;

        float res[4];
#pragma unroll
        for (int c = 0; c < 4; ++c) {
            float acc = b20;
#pragma unroll
            for (int k = 0; k < H; ++k) {
                float t = a[k] + bks[c][k];
                acc += fmaxf(t, 0.f) * w2[k];
            }
            res[c] = acc;
        }
        float4 o = make_float4(res[0], res[1], res[2], res[3]);
        *(float4*)(out + (size_t)i * N + j) = o;
    }
}

extern "C" void kernel_launch(void* const* d_in, const int* in_sizes, int n_in,
                              void* d_out, int out_size, void* d_ws, size_t ws_size,
                              hipStream_t stream) {
    const float* adj = (const float*)d_in[0];   // (1, N, N)
    const float* emb = (const float*)d_in[1];   // (1, F, N)
    const float* W1  = (const float*)d_in[2];   // (H, 2F+1)
    const float* b1  = (const float*)d_in[3];   // (H,)
    const float* W2  = (const float*)d_in[4];   // (8, H)
    const float* b2  = (const float*)d_in[5];   // (8,)
    float* out = (float*)d_out;

    float* partial = (float*)d_ws;              // RCHUNKS * N floats = 2 MB
    float* aj = partial + (size_t)RCHUNKS * N;  // N*H floats = 128 KB
    float* bk = aj + (size_t)N * H;             // N*H floats = 128 KB

    colsum_partial<<<dim3(4, RCHUNKS), 256, 0, stream>>>(adj, partial);
    build_ajbk<<<dim3(N / 256), 256, 0, stream>>>(adj, emb, W1, b1, partial, aj, bk);
    fuse_out<<<dim3(N / 128, N / 32), 256, 0, stream>>>(aj, bk, W2, b2, out);
}

// Round 5
// 48.023 us; speedup vs baseline: 1.2970x; 1.2970x over previous
//
#include <hip/hip_runtime.h>

#define N 4096
#define F 64
#define H 8
#define PCHUNKS 256   // row chunks for partial column sums (16 rows each)

// ---------------------------------------------------------------------------
// Kernel 1: partial column sums of A.
// grid (4, PCHUNKS) = 1024 blocks (4/CU), block 256. Each thread owns 4
// consecutive columns (float4 load), accumulates 16 rows, fully unrolled so
// loads batch for latency hiding. Coalesced 1KB/wave per instruction.
// ---------------------------------------------------------------------------
__global__ __launch_bounds__(256) void colsum_partial(const float* __restrict__ A,
                                                      float* __restrict__ partial) {
    int c4 = blockIdx.x * 256 + threadIdx.x;      // 0..1023 -> columns c4*4 .. +3
    int r0 = blockIdx.y * (N / PCHUNKS);
    const float* p = A + (size_t)r0 * N + (size_t)c4 * 4;
    float4 acc = make_float4(0.f, 0.f, 0.f, 0.f);
#pragma unroll
    for (int r = 0; r < N / PCHUNKS; ++r) {
        float4 v = *(const float4*)(p + (size_t)r * N);
        acc.x += v.x; acc.y += v.y; acc.z += v.z; acc.w += v.w;
    }
    *(float4*)(partial + (size_t)blockIdx.y * N + (size_t)c4 * 4) = acc;
}

// ---------------------------------------------------------------------------
// Kernel 2: finalize sum_w; compute aj[4096][8] (blocks 0..15) and
// bk[4096][8] (blocks 16..31). Split doubles CU coverage vs fused version.
//   aj[n][k] = b1[k] + sum_f E[n][f] * W1[k][f]
//   bk[n][k] = sum_w[n] * W1[k][128] + sum_f E[n][f] * W1[k][64+f]
// E[n][f] = emb[f*N + n] (coalesced). W1 reads wave-uniform -> scalar.
// ---------------------------------------------------------------------------
__global__ __launch_bounds__(256) void build_ajbk(const float* __restrict__ A,
                                                  const float* __restrict__ emb,
                                                  const float* __restrict__ W1,
                                                  const float* __restrict__ b1,
                                                  const float* __restrict__ partial,
                                                  float* __restrict__ aj,
                                                  float* __restrict__ bk) {
    int n = (blockIdx.x & 15) * 256 + threadIdx.x;
    bool do_bk = blockIdx.x >= 16;

    float e[F];
#pragma unroll
    for (int f = 0; f < F; ++f) e[f] = emb[(size_t)f * N + n];

    if (!do_bk) {
#pragma unroll
        for (int k = 0; k < H; ++k) {
            float a = b1[k];
#pragma unroll
            for (int f = 0; f < F; ++f) a += e[f] * W1[k * (2 * F + 1) + f];
            aj[n * H + k] = a;
        }
    } else {
        float s = 0.f;
#pragma unroll 16
        for (int p = 0; p < PCHUNKS; ++p) s += partial[(size_t)p * N + n];
        float sum_w = (s - A[(size_t)n * N + n]) * (1.0f / (float)(N - 1));
#pragma unroll
        for (int k = 0; k < H; ++k) {
            float b = sum_w * W1[k * (2 * F + 1) + 2 * F];
#pragma unroll
            for (int f = 0; f < F; ++f) b += e[f] * W1[k * (2 * F + 1) + F + f];
            bk[n * H + k] = b;
        }
    }
}

// ---------------------------------------------------------------------------
// Kernel 3: fused outer product + 8-wide relu-dot.
//   out[i][j] = b2[0] + sum_k relu(aj[i][k] + bk[j][k]) * W2[0][k]
// Tile: 128 rows x 128 cols per 256-thread block (16 rows x 4 cols / thread).
// The bk loads are per-lane 128B-contiguous gathers (64 L1 lines / instr);
// 16 rows per thread amortizes that gather cost 4x vs the 4-row version.
// Stores stay fully coalesced float4.
// ---------------------------------------------------------------------------
__global__ __launch_bounds__(256) void fuse_out(const float* __restrict__ aj,
                                                const float* __restrict__ bk,
                                                const float* __restrict__ W2,
                                                const float* __restrict__ b2,
                                                float* __restrict__ out) {
    int tx = threadIdx.x & 31;
    int ty = threadIdx.x >> 5;
    int j  = blockIdx.x * 128 + tx * 4;
    int i0 = blockIdx.y * 128 + ty * 16;

    float w2[H];
#pragma unroll
    for (int k = 0; k < H; ++k) w2[k] = W2[k];   // W2[0][k]
    float b20 = b2[0];

    float bks[4][H];
#pragma unroll
    for (int c = 0; c < 4; ++c) {
        float4 lo = *(const float4*)(bk + (size_t)(j + c) * H);
        float4 hi = *(const float4*)(bk + (size_t)(j + c) * H + 4);
        bks[c][0] = lo.x; bks[c][1] = lo.y; bks[c][2] = lo.z; bks[c][3] = lo.w;
        bks[c][4] = hi.x; bks[c][5] = hi.y; bks[c][6] = hi.z; bks[c][7] = hi.w;
    }

#pragma unroll
    for (int r = 0; r < 16; ++r) {
        int i = i0 + r;
        float a[H];
        float4 lo = *(const float4*)(aj + (size_t)i * H);
        float4 hi = *(const float4*)(aj + (size_t)i * H + 4);
        a[0] = lo.x; a[1] = lo.y; a[2] = lo.z; a[3] = lo.w;
        a[4] = hi.x; a[5] = hi.y; a[6] = hi.z; a[7] = hi.w;

        float res[4];
#pragma unroll
        for (int c = 0; c < 4; ++c) {
            float acc = b20;
#pragma unroll
            for (int k = 0; k < H; ++k) {
                float t = a[k] + bks[c][k];
                acc += fmaxf(t, 0.f) * w2[k];
            }
            res[c] = acc;
        }
        *(float4*)(out + (size_t)i * N + j) = make_float4(res[0], res[1], res[2], res[3]);
    }
}

extern "C" void kernel_launch(void* const* d_in, const int* in_sizes, int n_in,
                              void* d_out, int out_size, void* d_ws, size_t ws_size,
                              hipStream_t stream) {
    const float* adj = (const float*)d_in[0];   // (1, N, N)
    const float* emb = (const float*)d_in[1];   // (1, F, N)
    const float* W1  = (const float*)d_in[2];   // (H, 2F+1)
    const float* b1  = (const float*)d_in[3];   // (H,)
    const float* W2  = (const float*)d_in[4];   // (8, H)
    const float* b2  = (const float*)d_in[5];   // (8,)
    float* out = (float*)d_out;

    float* partial = (float*)d_ws;              // PCHUNKS * N floats = 4 MB
    float* aj = partial + (size_t)PCHUNKS * N;  // N*H floats = 128 KB
    float* bk = aj + (size_t)N * H;             // N*H floats = 128 KB

    colsum_partial<<<dim3(4, PCHUNKS), 256, 0, stream>>>(adj, partial);
    build_ajbk<<<dim3(32), 256, 0, stream>>>(adj, emb, W1, b1, partial, aj, bk);
    fuse_out<<<dim3(N / 128, N / 128), 256, 0, stream>>>(aj, bk, W2, b2, out);
}

// Round 7
// 40.797 us; speedup vs baseline: 1.5267x; 1.1771x over previous
//
#include <hip/hip_runtime.h>

#define N 4096
#define F 64
#define H 8
#define PCHUNKS 256   // row chunks for partial column sums (16 rows each)
#define W1S (2 * F + 1)   // 129, W1 row stride

// ---------------------------------------------------------------------------
// Kernel 1: partial column sums of A (known-good from R5).
// grid (4, PCHUNKS) = 1024 blocks, block 256. Each thread owns 4 consecutive
// columns (float4), accumulates 16 rows, fully unrolled.
// ---------------------------------------------------------------------------
__global__ __launch_bounds__(256) void colsum_partial(const float* __restrict__ A,
                                                      float* __restrict__ partial) {
    int c4 = blockIdx.x * 256 + threadIdx.x;
    int r0 = blockIdx.y * (N / PCHUNKS);
    const float* p = A + (size_t)r0 * N + (size_t)c4 * 4;
    float4 acc = make_float4(0.f, 0.f, 0.f, 0.f);
#pragma unroll
    for (int r = 0; r < N / PCHUNKS; ++r) {
        float4 v = *(const float4*)(p + (size_t)r * N);
        acc.x += v.x; acc.y += v.y; acc.z += v.z; acc.w += v.w;
    }
    *(float4*)(partial + (size_t)blockIdx.y * N + (size_t)c4 * 4) = acc;
}

// ---------------------------------------------------------------------------
// Kernel 2: per 128x128 output tile, self-contained:
//   stage A1: all threads reduce partial[256][cols] for this tile's 128 cols
//   stage A2: warps 0-1 -> bk[128][8] (needs sum_w); warps 2-3 -> aj[128][8]
//             both into LDS [128][12] (48B stride: float4-aligned rows)
//   stage B : out[i][j] = b2[0] + sum_k relu(aj[i][k]+bk[j][k])*W2[0][k]
//             aj LDS reads are same-address broadcasts (conflict-free);
//             bk loaded once into regs; stores coalesced float4.
// ---------------------------------------------------------------------------
__global__ __launch_bounds__(256) void fuse_tile(const float* __restrict__ A,
                                                 const float* __restrict__ emb,
                                                 const float* __restrict__ W1,
                                                 const float* __restrict__ b1,
                                                 const float* __restrict__ W2,
                                                 const float* __restrict__ b2,
                                                 const float* __restrict__ partial,
                                                 float* __restrict__ out) {
    __shared__ float ajs[128][12];
    __shared__ float bks_s[128][12];
    __shared__ float psum[128][2];

    const int t  = threadIdx.x;
    const int j0 = blockIdx.x * 128;
    const int i0 = blockIdx.y * 128;

    // ---- A1: column-sum reduction over partial chunks (split 2 ways) ----
    {
        int c = t & 127;            // column within tile
        int half = t >> 7;          // 0: chunks 0..127, 1: chunks 128..255
        const float* pp = partial + (size_t)half * 128 * N + (size_t)j0 + c;
        float s = 0.f;
#pragma unroll 16
        for (int p = 0; p < 128; ++p) s += pp[(size_t)p * N];
        psum[c][half] = s;
    }
    __syncthreads();

    // ---- A2: MLP rows into LDS ----
    if (t < 128) {
        int j = j0 + t;
        float sw = (psum[t][0] + psum[t][1] - A[(size_t)j * N + j]) * (1.0f / (float)(N - 1));
        float b[H];
#pragma unroll
        for (int k = 0; k < H; ++k) b[k] = sw * W1[k * W1S + 2 * F];
#pragma unroll
        for (int f = 0; f < F; ++f) {
            float e = emb[(size_t)f * N + j];
#pragma unroll
            for (int k = 0; k < H; ++k) b[k] += e * W1[k * W1S + F + f];
        }
#pragma unroll
        for (int k = 0; k < H; ++k) bks_s[t][k] = b[k];
    } else {
        int r = t - 128;
        int i = i0 + r;
        float a[H];
#pragma unroll
        for (int k = 0; k < H; ++k) a[k] = b1[k];
#pragma unroll
        for (int f = 0; f < F; ++f) {
            float e = emb[(size_t)f * N + i];
#pragma unroll
            for (int k = 0; k < H; ++k) a[k] += e * W1[k * W1S + f];
        }
#pragma unroll
        for (int k = 0; k < H; ++k) ajs[r][k] = a[k];
    }
    __syncthreads();

    // ---- B: fused outer product + relu-dot ----
    int tx = t & 31;
    int ty = t >> 5;
    int j  = j0 + tx * 4;

    float w2[H];
#pragma unroll
    for (int k = 0; k < H; ++k) w2[k] = W2[k];   // W2[0][k]
    float b20 = b2[0];

    float bkr[4][H];
#pragma unroll
    for (int c = 0; c < 4; ++c) {
        float4 lo = *(const float4*)&bks_s[tx * 4 + c][0];
        float4 hi = *(const float4*)&bks_s[tx * 4 + c][4];
        bkr[c][0] = lo.x; bkr[c][1] = lo.y; bkr[c][2] = lo.z; bkr[c][3] = lo.w;
        bkr[c][4] = hi.x; bkr[c][5] = hi.y; bkr[c][6] = hi.z; bkr[c][7] = hi.w;
    }

#pragma unroll
    for (int r = 0; r < 16; ++r) {
        int row = ty * 16 + r;
        float a[H];
        float4 lo = *(const float4*)&ajs[row][0];   // broadcast: all lanes same addr
        float4 hi = *(const float4*)&ajs[row][4];
        a[0] = lo.x; a[1] = lo.y; a[2] = lo.z; a[3] = lo.w;
        a[4] = hi.x; a[5] = hi.y; a[6] = hi.z; a[7] = hi.w;

        float res[4];
#pragma unroll
        for (int c = 0; c < 4; ++c) {
            float acc = b20;
#pragma unroll
            for (int k = 0; k < H; ++k) {
                float tt = a[k] + bkr[c][k];
                acc += fmaxf(tt, 0.f) * w2[k];
            }
            res[c] = acc;
        }
        *(float4*)(out + (size_t)(i0 + row) * N + j) = make_float4(res[0], res[1], res[2], res[3]);
    }
}

extern "C" void kernel_launch(void* const* d_in, const int* in_sizes, int n_in,
                              void* d_out, int out_size, void* d_ws, size_t ws_size,
                              hipStream_t stream) {
    const float* adj = (const float*)d_in[0];   // (1, N, N)
    const float* emb = (const float*)d_in[1];   // (1, F, N)
    const float* W1  = (const float*)d_in[2];   // (H, 2F+1)
    const float* b1  = (const float*)d_in[3];   // (H,)
    const float* W2  = (const float*)d_in[4];   // (8, H)
    const float* b2  = (const float*)d_in[5];   // (8,)
    float* out = (float*)d_out;

    float* partial = (float*)d_ws;              // PCHUNKS * N floats = 4 MB

    colsum_partial<<<dim3(4, PCHUNKS), 256, 0, stream>>>(adj, partial);
    fuse_tile<<<dim3(N / 128, N / 128), 256, 0, stream>>>(adj, emb, W1, b1, W2, b2,
                                                          partial, out);
}